// Round 9
// baseline (181.045 us; speedup 1.0000x reference)
//
#include <hip/hip_runtime.h>

#define N_NODES 20000
#define N_EDGES 160000
#define N_PAIRS 50000
#define DMAX 48
#define LNODES 48
// F_IN = CHANNELS = 32, EDGE_DIM = 8

__device__ __forceinline__ float4 f4fma(float s, float4 w, float4 a) {
    a.x += s * w.x; a.y += s * w.y; a.z += s * w.z; a.w += s * w.w;
    return a;
}

__global__ void zero_cnt(int* __restrict__ c) {
    int t = blockIdx.x * blockDim.x + threadIdx.x;
    if (t < N_NODES) c[t] = 0;
}

// adjacency by target: slot -> (src node, edge id) packed int2
__global__ __launch_bounds__(256) void fill_adj(const int* __restrict__ ei,
                                                int* __restrict__ cnt,
                                                int2* __restrict__ adj) {
    int e = blockIdx.x * blockDim.x + threadIdx.x;
    if (e >= N_EDGES) return;
    int2 st = ((const int2*)ei)[e];  // x = src, y = tgt
    int slot = atomicAdd(&cnt[st.y], 1);
    if (slot < DMAX) adj[st.y * DMAX + slot] = make_int2(st.x, e);
}

// Fused layer: per-block gather of the G sufficient statistic for 48 target
// nodes into LDS, then dense GEMM against W' = [knw | knb | root] (verbatim
// concatenation, read from global: per-wave the 8 j-slices of one k-row are a
// single 128B line, L1/L2-resident).
//   G[n][d*32+i] = sum_{e->n} e_d * X[src_e][i]   d=0..7
//   G[n][256+i]  = sum_{e->n} X[src_e][i]          (knb term)
//   G[n][288+i]  = X[n][i]                          (root term)
// out[n][o] = sum_k G[n][k]*W'[k][o]
// mode 0: H[n][o] = relu(out + bias[o])
// mode 1: util[n] = db + sum_o relu(out + bias[o]) * dw[o]
__global__ __launch_bounds__(384) void layer_kernel(const float* __restrict__ X,
                                                    const float* __restrict__ E,
                                                    const int* __restrict__ cnt,
                                                    const int2* __restrict__ adj,
                                                    const float* __restrict__ knw,
                                                    const float* __restrict__ knb,
                                                    const float* __restrict__ root,
                                                    const float* __restrict__ bias,
                                                    const float* __restrict__ dw,
                                                    const float* __restrict__ db,
                                                    float* __restrict__ H,
                                                    float* __restrict__ util,
                                                    int mode) {
    __shared__ float Gs[LNODES * 324];  // 62208 B, stride 324 spreads banks
    int t = threadIdx.x;
    int nb = blockIdx.x * LNODES;

    // ---- phase 1: gather G into LDS (12 nodes per pass, 4 passes) ----
    {
        int lane = t & 31;
        int sub = t >> 5;  // 0..11
#pragma unroll
        for (int pass = 0; pass < 4; ++pass) {
            int ln = pass * 12 + sub;
            int n = nb + ln;
            float g0 = 0.f, g1 = 0.f, g2 = 0.f, g3 = 0.f;
            float g4 = 0.f, g5 = 0.f, g6 = 0.f, g7 = 0.f, g8 = 0.f, gr_ = 0.f;
            if (n < N_NODES) {
                int deg = min(cnt[n], DMAX);
                const int2* ap = adj + n * DMAX;
                for (int k = 0; k < deg; ++k) {
                    int2 se = ap[k];
                    const float4* e4 = (const float4*)(E + (size_t)se.y * 8);
                    float4 ea = e4[0], eb = e4[1];   // broadcast within half-wave
                    float xv = X[se.x * 32 + lane];  // 128B coalesced gather
                    g0 += ea.x * xv; g1 += ea.y * xv; g2 += ea.z * xv; g3 += ea.w * xv;
                    g4 += eb.x * xv; g5 += eb.y * xv; g6 += eb.z * xv; g7 += eb.w * xv;
                    g8 += xv;
                }
                gr_ = X[n * 32 + lane];
            }
            float* g = &Gs[ln * 324];
            g[0 * 32 + lane] = g0; g[1 * 32 + lane] = g1;
            g[2 * 32 + lane] = g2; g[3 * 32 + lane] = g3;
            g[4 * 32 + lane] = g4; g[5 * 32 + lane] = g5;
            g[6 * 32 + lane] = g6; g[7 * 32 + lane] = g7;
            g[256 + lane] = g8;
            g[288 + lane] = gr_;
        }
    }
    __syncthreads();

    // ---- phase 2: GEMM, thread (mg, j) -> node nb+mg, outputs 4j..4j+3 ----
    int mg = t >> 3, j = t & 7;
    const float* grow = &Gs[mg * 324];
    float4 a = make_float4(0.f, 0.f, 0.f, 0.f);

    const float4* Wk = (const float4*)knw;  // element (k,j4): Wk[k*8 + j]
    for (int k4 = 0; k4 < 64; ++k4) {
        float4 w0 = Wk[(k4 * 4 + 0) * 8 + j];
        float4 w1 = Wk[(k4 * 4 + 1) * 8 + j];
        float4 w2 = Wk[(k4 * 4 + 2) * 8 + j];
        float4 w3 = Wk[(k4 * 4 + 3) * 8 + j];
        float4 g = *(const float4*)&grow[k4 * 4];
        a = f4fma(g.x, w0, a); a = f4fma(g.y, w1, a);
        a = f4fma(g.z, w2, a); a = f4fma(g.w, w3, a);
    }
    const float4* Kb = (const float4*)knb;
#pragma unroll
    for (int k4 = 0; k4 < 8; ++k4) {
        float4 w0 = Kb[(k4 * 4 + 0) * 8 + j];
        float4 w1 = Kb[(k4 * 4 + 1) * 8 + j];
        float4 w2 = Kb[(k4 * 4 + 2) * 8 + j];
        float4 w3 = Kb[(k4 * 4 + 3) * 8 + j];
        float4 g = *(const float4*)&grow[256 + k4 * 4];
        a = f4fma(g.x, w0, a); a = f4fma(g.y, w1, a);
        a = f4fma(g.z, w2, a); a = f4fma(g.w, w3, a);
    }
    const float4* Rt = (const float4*)root;
#pragma unroll
    for (int k4 = 0; k4 < 8; ++k4) {
        float4 w0 = Rt[(k4 * 4 + 0) * 8 + j];
        float4 w1 = Rt[(k4 * 4 + 1) * 8 + j];
        float4 w2 = Rt[(k4 * 4 + 2) * 8 + j];
        float4 w3 = Rt[(k4 * 4 + 3) * 8 + j];
        float4 g = *(const float4*)&grow[288 + k4 * 4];
        a = f4fma(g.x, w0, a); a = f4fma(g.y, w1, a);
        a = f4fma(g.z, w2, a); a = f4fma(g.w, w3, a);
    }

    int n = nb + mg;
    float4 b = ((const float4*)bias)[j];
    if (mode == 0) {
        if (n < N_NODES) {
            float4 v;
            v.x = fmaxf(a.x + b.x, 0.f); v.y = fmaxf(a.y + b.y, 0.f);
            v.z = fmaxf(a.z + b.z, 0.f); v.w = fmaxf(a.w + b.w, 0.f);
            ((float4*)H)[n * 8 + j] = v;
        }
    } else {
        float4 dv = ((const float4*)dw)[j];
        float p = fmaxf(a.x + b.x, 0.f) * dv.x + fmaxf(a.y + b.y, 0.f) * dv.y
                + fmaxf(a.z + b.z, 0.f) * dv.z + fmaxf(a.w + b.w, 0.f) * dv.w;
        p += __shfl_xor(p, 1);
        p += __shfl_xor(p, 2);
        p += __shfl_xor(p, 4);
        if (j == 0 && n < N_NODES) util[n] = p + db[0];
    }
}

// out[p] = util[idx_b[p]] - util[idx_a[p]]
__global__ void pair_kernel(const float* __restrict__ util, const int* __restrict__ ia,
                            const int* __restrict__ ib, float* __restrict__ out) {
    int p = blockIdx.x * blockDim.x + threadIdx.x;
    if (p >= N_PAIRS) return;
    out[p] = util[ib[p]] - util[ia[p]];
}

extern "C" void kernel_launch(void* const* d_in, const int* in_sizes, int n_in,
                              void* d_out, int out_size, void* d_ws, size_t ws_size,
                              hipStream_t stream) {
    const float* x     = (const float*)d_in[0];
    const float* e     = (const float*)d_in[1];
    const float* knw1  = (const float*)d_in[2];
    const float* knb1  = (const float*)d_in[3];
    const float* root1 = (const float*)d_in[4];
    const float* bias1 = (const float*)d_in[5];
    const float* knw2  = (const float*)d_in[6];
    const float* knb2  = (const float*)d_in[7];
    const float* root2 = (const float*)d_in[8];
    const float* bias2 = (const float*)d_in[9];
    const float* dw    = (const float*)d_in[10];
    const float* db    = (const float*)d_in[11];
    const int*   ei    = (const int*)d_in[12];
    const int*   ia    = (const int*)d_in[13];
    const int*   ib    = (const int*)d_in[14];
    float* out = (float*)d_out;

    float* ws = (float*)d_ws;
    float* H    = ws;                       // 640,000 floats
    float* util = ws + 640000;              // 20,000
    int*   cnt  = (int*)(ws + 660000);      // 20,000
    int2*  adj  = (int2*)(ws + 680000);     // 960,000 int2 (8-byte aligned)

    int nblk = (N_NODES + LNODES - 1) / LNODES;  // 417

    // ---- adjacency ----
    zero_cnt<<<(N_NODES + 255) / 256, 256, 0, stream>>>(cnt);
    fill_adj<<<(N_EDGES + 255) / 256, 256, 0, stream>>>(ei, cnt, adj);

    // ---- layer 1 ----
    layer_kernel<<<nblk, 384, 0, stream>>>(x, e, cnt, adj, knw1, knb1, root1,
                                           bias1, dw, db, H, util, 0);
    // ---- layer 2 (+ readout) ----
    layer_kernel<<<nblk, 384, 0, stream>>>(H, e, cnt, adj, knw2, knb2, root2,
                                           bias2, dw, db, H, util, 1);

    // ---- pairs ----
    pair_kernel<<<(N_PAIRS + 255) / 256, 256, 0, stream>>>(util, ia, ib, out);
}